// Round 2
// baseline (112.350 us; speedup 1.0000x reference)
//
#include <hip/hip_runtime.h>
#include <stdint.h>

#define KN 9
#define HH 64
#define WW 64
#define CC 128
#define FF 128
#define TM 64      // pixels per block (one full image row)
#define NT 512     // threads per block (8 waves)
#define LDK 136    // padded LDS K-stride (bf16); 272 B row, 16B-aligned

typedef __bf16 bf16x8 __attribute__((ext_vector_type(8)));
typedef float f32x4 __attribute__((ext_vector_type(4)));
typedef unsigned short us8 __attribute__((ext_vector_type(8)));
typedef unsigned short us4 __attribute__((ext_vector_type(4)));

// Reference tap layout (verified R3): stack(meshgrid(ij)).reshape(-1,2)
__constant__ float c_init_i[KN] = {0.f,0.f,1.f,2.f,2.f,1.f,0.f,2.f,1.f};
__constant__ float c_init_j[KN] = {0.f,1.f,1.f,2.f,0.f,2.f,1.f,0.f,2.f};

static __device__ inline unsigned short f2bf(float f) {
    union { float f; unsigned u; } v; v.f = f;
    unsigned r = v.u + 0x7fffu + ((v.u >> 16) & 1u);  // RNE
    return (unsigned short)(r >> 16);
}

// Transpose + quantize W: (KN, C, F) fp32 -> Wt bf16 in B-FRAGMENT layout:
//   idx = n*16384 + (c>>5)*4096 + f*32 + (c&31)
// so a wave's MFMA B-fragment load (16 f-rows x 64B) is one contiguous 1KB read.
__global__ void wt_kernel(const float* __restrict__ Wk, unsigned short* __restrict__ Wt) {
    __shared__ unsigned short t[32][33];
    const int tid = threadIdx.x;
    const int n  = blockIdx.x >> 4;
    const int tf = blockIdx.x & 3;        // f-tile
    const int tc = (blockIdx.x >> 2) & 3; // c-tile (== ks)
    const int g  = tid >> 5;              // 0..7
    const int l  = tid & 31;
#pragma unroll
    for (int r = 0; r < 4; ++r) {
        int cl = g * 4 + r;
        t[cl][l] = f2bf(Wk[(n << 14) + ((tc * 32 + cl) << 7) + (tf * 32 + l)]);
    }
    __syncthreads();
#pragma unroll
    for (int r = 0; r < 4; ++r) {
        int fl = g * 4 + r;
        Wt[(n << 14) + (tc << 12) + ((tf * 32 + fl) << 5) + l] = t[l][fl];
    }
}

// issue 4 corner loads (4 channels each) into NAMED float4 regs, pin with sched_barrier
#define ISSUE(n_, p_, S) do {                                          \
    int4 cb_ = *(const int4*)&cB[p_][n_][0];                           \
    lt##S = *(const float4*)(bbase + cb_.x + icg);                     \
    rt##S = *(const float4*)(bbase + cb_.y + icg);                     \
    lb##S = *(const float4*)(bbase + cb_.z + icg);                     \
    rb##S = *(const float4*)(bbase + cb_.w + icg);                     \
    __builtin_amdgcn_sched_barrier(0);                                 \
  } while (0)

// bilinear interp of 4 channels + bf16 pack + one ds_write_b64
#define CONSUME(n_, p_, S) do {                                        \
    float fy_ = cF[p_][n_][0], fx_ = cF[p_][n_][1];                    \
    us4 pk_;                                                           \
    _Pragma("unroll")                                                  \
    for (int j = 0; j < 4; ++j) {                                      \
      float v0_ = lt##S[j], v1_ = rt##S[j], v2_ = lb##S[j], v3_ = rb##S[j]; \
      float vt_ = v0_ + (v1_ - v0_) * fy_;                             \
      float vb_ = v2_ + (v3_ - v2_) * fy_;                             \
      float r_  = vt_ + (vb_ - vt_) * fx_;                             \
      pk_[j] = __builtin_bit_cast(unsigned short, (__bf16)r_);         \
    }                                                                  \
    *(us4*)&As[d][p_][icg] = pk_;                                      \
  } while (0)

#define MSTEP(ks_, B0, B1) do {                                        \
    bf16x8 a0_ = __builtin_bit_cast(bf16x8, *(const us8*)(&As[d][mtile + col][(ks_) * 32 + quad * 8]));      \
    bf16x8 a1_ = __builtin_bit_cast(bf16x8, *(const us8*)(&As[d][mtile + 16 + col][(ks_) * 32 + quad * 8])); \
    acc00 = __builtin_amdgcn_mfma_f32_16x16x32_bf16(a0_, __builtin_bit_cast(bf16x8, B0), acc00, 0, 0, 0);    \
    acc01 = __builtin_amdgcn_mfma_f32_16x16x32_bf16(a0_, __builtin_bit_cast(bf16x8, B1), acc01, 0, 0, 0);    \
    acc10 = __builtin_amdgcn_mfma_f32_16x16x32_bf16(a1_, __builtin_bit_cast(bf16x8, B0), acc10, 0, 0, 0);    \
    acc11 = __builtin_amdgcn_mfma_f32_16x16x32_bf16(a1_, __builtin_bit_cast(bf16x8, B1), acc11, 0, 0, 0);    \
  } while (0)

__launch_bounds__(NT, 4)   // 128 VGPR cap: 2 blocks/CU
__global__ void deform_kernel(const float* __restrict__ xin,
                              const float* __restrict__ off,
                              const unsigned short* __restrict__ Wt,
                              const float* __restrict__ bias,
                              float* __restrict__ out) {
    __shared__ unsigned short As[2][TM][LDK];  // double-buffered A tile: 34816 B
    __shared__ int   cB[TM][KN][4];            // corner element-offsets: 9216 B
    __shared__ float cF[TM][KN][2];            // (fy, fx): 4608 B
    // total 48640 B -> 2 blocks/CU

    const int tid = threadIdx.x;
    // XCD swizzle (verified R5: FETCH 196->10.5 MB): image b -> XCD b.
    const int bb   = blockIdx.x & 7;
    const int hh   = blockIdx.x >> 3;
    const int pix0 = (bb << 12) + (hh << 6);

    // ---- phase 0: corner offsets + fractions once per (p, n) ----
    for (int t = tid; t < TM * KN; t += NT) {
        int p = t & (TM - 1);
        int n = t >> 6;
        float2 o = *(const float2*)(off + (size_t)(pix0 + p) * (2 * KN) + 2 * n);
        float y = (float)(hh - 1) + c_init_i[n] + o.x;
        float x = (float)(p - 1) + c_init_j[n] + o.y;
        y = fminf(fmaxf(y, 0.f), 63.f);
        x = fminf(fmaxf(x, 0.f), 63.f);
        float y0f = floorf(y), x0f = floorf(x);
        int y0 = (int)y0f, x0 = (int)x0f;
        int y1 = (int)ceilf(y), x1 = (int)ceilf(x);
        cB[p][n][0] = ((y0 << 6) + x0) << 7;   // lt
        cB[p][n][1] = ((y1 << 6) + x0) << 7;   // rt (y1, x0) per TF coords_rt
        cB[p][n][2] = ((y0 << 6) + x1) << 7;   // lb (y0, x1) per TF coords_lb
        cB[p][n][3] = ((y1 << 6) + x1) << 7;   // rb
        cF[p][n][0] = y - y0f;
        cF[p][n][1] = x - x0f;
    }

    const int wave = tid >> 6;
    const int lane = tid & 63;
    const int quad = lane >> 4;
    const int col  = lane & 15;
    const int mtile = (wave & 1) * 32;   // 2 M-supertiles of 32 pixels
    const int ntile = (wave >> 1) * 32;  // 4 N-supertiles of 32 filters

    f32x4 acc00 = {0.f,0.f,0.f,0.f}, acc01 = {0.f,0.f,0.f,0.f};
    f32x4 acc10 = {0.f,0.f,0.f,0.f}, acc11 = {0.f,0.f,0.f,0.f};

    const float* bbase = xin + ((size_t)bb << 19);
    // B-fragment base: f = ntile+col (+16), c-chunk = quad*8
    const unsigned short* wb0 = Wt + ((ntile + col) << 5) + (quad << 3);

    // gather decomposition: item k handles i = tid + k*NT, k = 0..3
    //   p = ip + 16k (row), channel group = (tid&31)*4
    const int ip  = tid >> 5;
    const int icg = (tid & 31) * 4;

    // named prefetch registers (rolling A/B double buffer)
    float4 ltA, rtA, lbA, rbA;
    float4 ltB, rtB, lbB, rbB;
    us8 bfr0, bfr1, bfr2, bfr3, bfr4, bfr5, bfr6, bfr7;

    __syncthreads();   // coords ready (full drain fine, once)

    int d = 0;
    ISSUE(0, ip, A);   // prologue: tap 0, item 0

    for (int n = 0; n < KN; ++n, d ^= 1) {
        // B fragments for tap n, direct from L2 (Wt 294KB, L2-resident).
        // In flight across the whole gather phase AND the lgkm-only barrier.
        const unsigned short* wn = wb0 + (n << 14);
        bfr0 = *(const us8*)(wn);
        bfr1 = *(const us8*)(wn + 512);
        bfr2 = *(const us8*)(wn + 4096);
        bfr3 = *(const us8*)(wn + 4096 + 512);
        bfr4 = *(const us8*)(wn + 8192);
        bfr5 = *(const us8*)(wn + 8192 + 512);
        bfr6 = *(const us8*)(wn + 12288);
        bfr7 = *(const us8*)(wn + 12288 + 512);
        __builtin_amdgcn_sched_barrier(0);

        ISSUE(n, ip + 16, B);
        CONSUME(n, ip, A);
        ISSUE(n, ip + 32, A);
        CONSUME(n, ip + 16, B);
        ISSUE(n, ip + 48, B);
        CONSUME(n, ip + 32, A);
        CONSUME(n, ip + 48, B);

        // lgkm-only barrier: As[d] ds_writes drained; global loads stay in flight
        asm volatile("s_waitcnt lgkmcnt(0)" ::: "memory");
        __builtin_amdgcn_s_barrier();

        // next tap's item 0 rides under the MFMA phase
        if (n + 1 < KN) ISSUE(n + 1, ip, A);

        MSTEP(0, bfr0, bfr1);
        MSTEP(1, bfr2, bfr3);
        MSTEP(2, bfr4, bfr5);
        MSTEP(3, bfr6, bfr7);
        // no trailing barrier: next tap writes As[d^1]; As[d] reuse is 2 taps
        // away, separated by next tap's barrier.
    }

    // ---- epilogue: C/D layout col=lane&15, row=quad*4+reg (HW-verified) ----
#pragma unroll
    for (int b = 0; b < 2; ++b) {
        int f = ntile + b * 16 + col;
        float bv = bias[f];
        const f32x4 ac0 = b ? acc01 : acc00;
        const f32x4 ac1 = b ? acc11 : acc10;
#pragma unroll
        for (int r = 0; r < 4; ++r) {
            int pr0 = pix0 + mtile + quad * 4 + r;
            out[(size_t)pr0 * FF + f] = ac0[r] + bv;
            int pr1 = pr0 + 16;
            out[(size_t)pr1 * FF + f] = ac1[r] + bv;
        }
    }
}

extern "C" void kernel_launch(void* const* d_in, const int* in_sizes, int n_in,
                              void* d_out, int out_size, void* d_ws, size_t ws_size,
                              hipStream_t stream) {
    const float* x    = (const float*)d_in[0];
    const float* off  = (const float*)d_in[1];
    const float* Wk   = (const float*)d_in[2];
    const float* bias = (const float*)d_in[3];
    float* out = (float*)d_out;
    unsigned short* Wt = (unsigned short*)d_ws;  // 9*128*128 bf16 = 294912 B

    wt_kernel<<<KN * 16, 256, 0, stream>>>(Wk, Wt);
    deform_kernel<<<(8 * HH * WW) / TM, NT, 0, stream>>>(x, off, Wt, bias, out);
}

// Round 3
// 101.103 us; speedup vs baseline: 1.1112x; 1.1112x over previous
//
#include <hip/hip_runtime.h>
#include <stdint.h>

#define KN 9
#define HH 64
#define WW 64
#define CC 128
#define FF 128
#define TM 64      // pixels per block (one full image row)
#define NT 512     // threads per block (8 waves)
#define LDK 136    // padded LDS K-stride (bf16); 272 B row, 16B-aligned

typedef __bf16 bf16x8 __attribute__((ext_vector_type(8)));
typedef float f32x4 __attribute__((ext_vector_type(4)));
typedef unsigned short us8 __attribute__((ext_vector_type(8)));

__constant__ float c_init_i[KN] = {0.f,0.f,1.f,2.f,2.f,1.f,0.f,2.f,1.f};
__constant__ float c_init_j[KN] = {0.f,1.f,1.f,2.f,0.f,2.f,1.f,0.f,2.f};

static __device__ inline float bf2f(unsigned short u) {
    union { unsigned u; float f; } v; v.u = ((unsigned)u) << 16; return v.f;
}

// x fp32 -> bf16 (halves gather VMEM traffic in deform_kernel)
__global__ void xb_kernel(const float* __restrict__ x, unsigned short* __restrict__ xb) {
    int i = (blockIdx.x * 256 + threadIdx.x) * 8;
    float4 a = *(const float4*)(x + i);
    float4 b = *(const float4*)(x + i + 4);
    us8 o;
    o[0] = __builtin_bit_cast(unsigned short, (__bf16)a.x);
    o[1] = __builtin_bit_cast(unsigned short, (__bf16)a.y);
    o[2] = __builtin_bit_cast(unsigned short, (__bf16)a.z);
    o[3] = __builtin_bit_cast(unsigned short, (__bf16)a.w);
    o[4] = __builtin_bit_cast(unsigned short, (__bf16)b.x);
    o[5] = __builtin_bit_cast(unsigned short, (__bf16)b.y);
    o[6] = __builtin_bit_cast(unsigned short, (__bf16)b.z);
    o[7] = __builtin_bit_cast(unsigned short, (__bf16)b.w);
    *(us8*)(xb + i) = o;
}

// W (KN,C,F) fp32 -> Wt bf16 in WAVE-LINEAR fragment layout:
//   elem = slot*512 + quad*128 + col*8 + e,  slot = ((n*4+ks)*4+g)*2 + b
// where f = g*32 + b*16 + col, c = ks*32 + quad*8 + e.  Each wave's B-frag
// is then a contiguous 1KB chunk (lane*16B): conflict-free LDS reads and a
// linear global_load_lds staging copy.
__global__ void wt_kernel(const float* __restrict__ Wk, unsigned short* __restrict__ Wt) {
    __shared__ unsigned short t[32][33];
    const int tid = threadIdx.x;
    const int n  = blockIdx.x >> 4;
    const int tf = blockIdx.x & 3;        // f-tile (g)
    const int tc = (blockIdx.x >> 2) & 3; // c-tile (ks)
    const int g  = tid >> 5;
    const int l  = tid & 31;
#pragma unroll
    for (int r = 0; r < 4; ++r) {
        int cl = g * 4 + r;
        t[cl][l] = __builtin_bit_cast(unsigned short,
                    (__bf16)Wk[(n << 14) + ((tc * 32 + cl) << 7) + (tf * 32 + l)]);
    }
    __syncthreads();
#pragma unroll
    for (int r = 0; r < 4; ++r) {
        int o   = r * 256 + tid;          // 0..1023 within this (n,ks,g) tile
        int b   = o >> 9;
        int q   = (o >> 7) & 3;
        int col = (o >> 3) & 15;
        int e   = o & 7;
        Wt[(((n * 4 + tc) * 4 + tf) << 10) + o] = t[q * 8 + e][b * 16 + col];
    }
}

// issue 4 corner loads (8 bf16 channels each) into NAMED us8 regs
#define ISSUE(n_, s_, S) do {                                          \
    int p_ = (s_) >> 4; int ch_ = ((s_) & 15) * 8;                     \
    int lt_o = cB[p_][n_][0], rb_o = cB[p_][n_][1];                    \
    int rt_o = (rb_o & 0x7E000) | (lt_o & 0x1F80);                     \
    int lb_o = (lt_o & 0x7E000) | (rb_o & 0x1F80);                     \
    lt##S = *(const us8*)(bb16 + lt_o + ch_);                          \
    rt##S = *(const us8*)(bb16 + rt_o + ch_);                          \
    lb##S = *(const us8*)(bb16 + lb_o + ch_);                          \
    rb##S = *(const us8*)(bb16 + rb_o + ch_);                          \
    __builtin_amdgcn_sched_barrier(0);                                 \
  } while (0)

// bilinear interp of 8 channels + bf16 pack + one ds_write_b128
#define CONSUME(n_, s_, S) do {                                        \
    int p_ = (s_) >> 4; int ch_ = ((s_) & 15) * 8;                     \
    float fy_ = cF[p_][n_][0], fx_ = cF[p_][n_][1];                    \
    us8 pk_;                                                           \
    _Pragma("unroll")                                                  \
    for (int j = 0; j < 8; ++j) {                                      \
      float v0_ = bf2f(lt##S[j]), v1_ = bf2f(rt##S[j]);                \
      float v2_ = bf2f(lb##S[j]), v3_ = bf2f(rb##S[j]);                \
      float vt_ = v0_ + (v1_ - v0_) * fy_;                             \
      float vb_ = v2_ + (v3_ - v2_) * fy_;                             \
      float r_  = vt_ + (vb_ - vt_) * fx_;                             \
      pk_[j] = __builtin_bit_cast(unsigned short, (__bf16)r_);         \
    }                                                                  \
    *(us8*)&As[p_][ch_] = pk_;                                         \
  } while (0)

#define MSTEP(ks_) do {                                                \
    bf16x8 a0_ = __builtin_bit_cast(bf16x8, *(const us8*)(&As[mtile + col][(ks_) * 32 + quad * 8]));      \
    bf16x8 a1_ = __builtin_bit_cast(bf16x8, *(const us8*)(&As[mtile + 16 + col][(ks_) * 32 + quad * 8])); \
    bf16x8 b0_ = __builtin_bit_cast(bf16x8, *(const us8*)(&Bt[(((ks_) * 4 + gi) * 2 + 0) * 512 + lane * 8])); \
    bf16x8 b1_ = __builtin_bit_cast(bf16x8, *(const us8*)(&Bt[(((ks_) * 4 + gi) * 2 + 1) * 512 + lane * 8])); \
    acc00 = __builtin_amdgcn_mfma_f32_16x16x32_bf16(a0_, b0_, acc00, 0, 0, 0);    \
    acc01 = __builtin_amdgcn_mfma_f32_16x16x32_bf16(a0_, b1_, acc01, 0, 0, 0);    \
    acc10 = __builtin_amdgcn_mfma_f32_16x16x32_bf16(a1_, b0_, acc10, 0, 0, 0);    \
    acc11 = __builtin_amdgcn_mfma_f32_16x16x32_bf16(a1_, b1_, acc11, 0, 0, 0);    \
  } while (0)

// stage tap n_'s 32KB W slice into Bt via global_load_lds (linear copy)
typedef __attribute__((address_space(3))) unsigned int lds_u32;
typedef __attribute__((address_space(1))) const unsigned int glb_u32;
#define STAGE_BT(n_) do {                                              \
    const unsigned int* src_ = (const unsigned int*)(Wt + ((size_t)(n_) << 14)); \
    _Pragma("unroll")                                                  \
    for (int r_ = 0; r_ < 4; ++r_) {                                   \
      __builtin_amdgcn_global_load_lds(                                \
          (glb_u32*)(src_ + (r_ << 11) + (wave << 8) + (lane << 2)),   \
          (lds_u32*)((unsigned int*)Bt + (r_ << 11) + (wave << 8)),    \
          16, 0, 0);                                                   \
    }                                                                  \
  } while (0)

__launch_bounds__(NT, 4)   // 128 VGPR cap: 2 blocks/CU
__global__ void deform_kernel(const unsigned short* __restrict__ xb,
                              const float* __restrict__ off,
                              const unsigned short* __restrict__ Wt,
                              const float* __restrict__ bias,
                              float* __restrict__ out) {
    __shared__ unsigned short As[TM][LDK];   // 17408 B (single buffer)
    __shared__ unsigned short Bt[16384];     // 32768 B: one tap's W fragments
    __shared__ int   cB[TM][KN][2];          // packed lt/rb offsets: 4608 B
    __shared__ float cF[TM][KN][2];          // (fy, fx): 4608 B
    // total 59392 B -> 2 blocks/CU

    const int tid = threadIdx.x;
    const int bb   = blockIdx.x & 7;         // XCD swizzle: image b -> XCD b
    const int hh   = blockIdx.x >> 3;
    const int pix0 = (bb << 12) + (hh << 6);

    // ---- phase 0: packed corner offsets + fractions per (p, n) ----
    for (int t = tid; t < TM * KN; t += NT) {
        int p = t & (TM - 1);
        int n = t >> 6;
        float2 o = *(const float2*)(off + (size_t)(pix0 + p) * (2 * KN) + 2 * n);
        float y = (float)(hh - 1) + c_init_i[n] + o.x;
        float x = (float)(p - 1) + c_init_j[n] + o.y;
        y = fminf(fmaxf(y, 0.f), 63.f);
        x = fminf(fmaxf(x, 0.f), 63.f);
        float y0f = floorf(y), x0f = floorf(x);
        int y0 = (int)y0f, x0 = (int)x0f;
        int y1 = (int)ceilf(y), x1 = (int)ceilf(x);
        cB[p][n][0] = (y0 << 13) | (x0 << 7);   // lt element offset
        cB[p][n][1] = (y1 << 13) | (x1 << 7);   // rb element offset
        cF[p][n][0] = y - y0f;
        cF[p][n][1] = x - x0f;
    }

    const int wave = tid >> 6;
    const int lane = tid & 63;
    const int quad = lane >> 4;
    const int col  = lane & 15;
    const int mtile = (wave & 1) * 32;
    const int ntile = (wave >> 1) * 32;
    const int gi    = wave >> 1;

    f32x4 acc00 = {0.f,0.f,0.f,0.f}, acc01 = {0.f,0.f,0.f,0.f};
    f32x4 acc10 = {0.f,0.f,0.f,0.f}, acc11 = {0.f,0.f,0.f,0.f};

    const unsigned short* bb16 = xb + ((size_t)bb << 19);

    // gather: 2 items/thread/tap; item slot s covers pixel s>>4, channels (s&15)*8
    us8 ltA, rtA, lbA, rbA;
    us8 ltB, rtB, lbB, rbB;

    __syncthreads();   // coords ready

    STAGE_BT(0);       // W slice for tap 0 -> Bt (in flight)
    ISSUE(0, tid, A);  // tap 0, item 0

    for (int n = 0; n < KN; ++n) {
        ISSUE(n, tid + NT, B);
        CONSUME(n, tid, A);
        CONSUME(n, tid + NT, B);
        __syncthreads();   // As + Bt(n) ready (vmcnt0 + lgkm0 drain)

        // next tap's item 0 rides under the MFMA phase
        if (n + 1 < KN) ISSUE(n + 1, tid, A);

        MSTEP(0);
        MSTEP(1);
        MSTEP(2);
        MSTEP(3);

        __builtin_amdgcn_s_barrier();   // all waves done reading As/Bt
        if (n + 1 < KN) STAGE_BT(n + 1); // overwrite Bt under next gather phase
    }

    // ---- epilogue: C/D layout col=lane&15, row=quad*4+reg (HW-verified) ----
#pragma unroll
    for (int b = 0; b < 2; ++b) {
        int f = ntile + b * 16 + col;
        float bv = bias[f];
        const f32x4 ac0 = b ? acc01 : acc00;
        const f32x4 ac1 = b ? acc11 : acc10;
#pragma unroll
        for (int r = 0; r < 4; ++r) {
            int pr0 = pix0 + mtile + quad * 4 + r;
            out[(size_t)pr0 * FF + f] = ac0[r] + bv;
            int pr1 = pr0 + 16;
            out[(size_t)pr1 * FF + f] = ac1[r] + bv;
        }
    }
}

extern "C" void kernel_launch(void* const* d_in, const int* in_sizes, int n_in,
                              void* d_out, int out_size, void* d_ws, size_t ws_size,
                              hipStream_t stream) {
    const float* x    = (const float*)d_in[0];
    const float* off  = (const float*)d_in[1];
    const float* Wk   = (const float*)d_in[2];
    const float* bias = (const float*)d_in[3];
    float* out = (float*)d_out;
    unsigned short* Wt = (unsigned short*)d_ws;            // 294912 B
    unsigned short* xb = (unsigned short*)d_ws + 147456;   // 8 MB bf16 x

    xb_kernel<<<2048, 256, 0, stream>>>(x, xb);
    wt_kernel<<<KN * 16, 256, 0, stream>>>(Wk, Wt);
    deform_kernel<<<(8 * HH * WW) / TM, NT, 0, stream>>>(xb, off, Wt, bias, out);
}

// Round 5
// 100.493 us; speedup vs baseline: 1.1180x; 1.0061x over previous
//
#include <hip/hip_runtime.h>
#include <stdint.h>

#define KN 9
#define HH 64
#define WW 64
#define CC 128
#define FF 128
#define TM 64      // pixels per block (one full image row)
#define NT 512     // threads per block (8 waves)
#define LDK 136    // padded LDS K-stride (bf16); 272 B row, 16B-aligned

typedef __bf16 bf16x8 __attribute__((ext_vector_type(8)));
typedef float f32x4 __attribute__((ext_vector_type(4)));
typedef unsigned short us8 __attribute__((ext_vector_type(8)));

__constant__ float c_init_i[KN] = {0.f,0.f,1.f,2.f,2.f,1.f,0.f,2.f,1.f};
__constant__ float c_init_j[KN] = {0.f,1.f,1.f,2.f,0.f,2.f,1.f,0.f,2.f};

static __device__ inline float bf2f(unsigned short u) {
    union { unsigned u; float f; } v; v.u = ((unsigned)u) << 16; return v.f;
}

// Merged prep: blocks 0..143 transpose W; blocks 144..2191 convert x to bf16.
// W (KN,C,F) fp32 -> Wt bf16 in WAVE-LINEAR fragment layout:
//   elem = slot*512 + quad*128 + col*8 + e,  slot = ((n*4+ks)*4+g)*2 + b
//   f = g*32 + b*16 + col, c = ks*32 + quad*8 + e
// Each wave's B-frag is a contiguous 1KB chunk (lane*8 elems): perfectly
// coalesced direct-from-L2 register loads in deform_kernel.
__global__ void prep_kernel(const float* __restrict__ Wk, unsigned short* __restrict__ Wt,
                            const float* __restrict__ x, unsigned short* __restrict__ xb) {
    __shared__ unsigned short t[32][33];
    const int tid = threadIdx.x;
    if (blockIdx.x >= 144) {
        int i = ((blockIdx.x - 144) * 256 + tid) * 8;
        float4 a = *(const float4*)(x + i);
        float4 b = *(const float4*)(x + i + 4);
        us8 o;
        o[0] = __builtin_bit_cast(unsigned short, (__bf16)a.x);
        o[1] = __builtin_bit_cast(unsigned short, (__bf16)a.y);
        o[2] = __builtin_bit_cast(unsigned short, (__bf16)a.z);
        o[3] = __builtin_bit_cast(unsigned short, (__bf16)a.w);
        o[4] = __builtin_bit_cast(unsigned short, (__bf16)b.x);
        o[5] = __builtin_bit_cast(unsigned short, (__bf16)b.y);
        o[6] = __builtin_bit_cast(unsigned short, (__bf16)b.z);
        o[7] = __builtin_bit_cast(unsigned short, (__bf16)b.w);
        *(us8*)(xb + i) = o;
        return;
    }
    const int n  = blockIdx.x >> 4;
    const int tf = blockIdx.x & 3;        // f-tile (g)
    const int tc = (blockIdx.x >> 2) & 3; // c-tile (ks)
    const int g  = tid >> 5;
    const int l  = tid & 31;
#pragma unroll
    for (int r = 0; r < 4; ++r) {
        int cl = g * 4 + r;
        t[cl][l] = __builtin_bit_cast(unsigned short,
                    (__bf16)Wk[(n << 14) + ((tc * 32 + cl) << 7) + (tf * 32 + l)]);
    }
    __syncthreads();
#pragma unroll
    for (int r = 0; r < 4; ++r) {
        int o   = r * 256 + tid;          // 0..1023 within this (n,ks,g) tile
        int b   = o >> 9;
        int q   = (o >> 7) & 3;
        int col = (o >> 3) & 15;
        int e   = o & 7;
        Wt[(((n * 4 + tc) * 4 + tf) << 10) + o] = t[q * 8 + e][b * 16 + col];
    }
}

// issue 4 corner loads (8 bf16 channels each) into NAMED us8 regs
#define ISSUE(n_, s_, S) do {                                          \
    int p_ = (s_) >> 4; int ch_ = ((s_) & 15) * 8;                     \
    int lt_o = cB[p_][n_][0], rb_o = cB[p_][n_][1];                    \
    int rt_o = (rb_o & 0x7E000) | (lt_o & 0x1F80);                     \
    int lb_o = (lt_o & 0x7E000) | (rb_o & 0x1F80);                     \
    lt##S = *(const us8*)(bb16 + lt_o + ch_);                          \
    rt##S = *(const us8*)(bb16 + rt_o + ch_);                          \
    lb##S = *(const us8*)(bb16 + lb_o + ch_);                          \
    rb##S = *(const us8*)(bb16 + rb_o + ch_);                          \
    __builtin_amdgcn_sched_barrier(0);                                 \
  } while (0)

// bilinear interp of 8 channels + bf16 pack + one ds_write_b128
#define CONSUME(n_, s_, S) do {                                        \
    int p_ = (s_) >> 4; int ch_ = ((s_) & 15) * 8;                     \
    float fy_ = cF[p_][n_][0], fx_ = cF[p_][n_][1];                    \
    us8 pk_;                                                           \
    _Pragma("unroll")                                                  \
    for (int j = 0; j < 8; ++j) {                                      \
      float v0_ = bf2f(lt##S[j]), v1_ = bf2f(rt##S[j]);                \
      float v2_ = bf2f(lb##S[j]), v3_ = bf2f(rb##S[j]);                \
      float vt_ = v0_ + (v1_ - v0_) * fy_;                             \
      float vb_ = v2_ + (v3_ - v2_) * fy_;                             \
      float r_  = vt_ + (vb_ - vt_) * fx_;                             \
      pk_[j] = __builtin_bit_cast(unsigned short, (__bf16)r_);         \
    }                                                                  \
    *(us8*)&As[d][p_][ch_] = pk_;                                      \
  } while (0)

// B-fragment loads for tap n_, direct from L2, fully coalesced (1KB/wave/frag)
#define LOADB(n_) do {                                                 \
    const unsigned short* wn_ = wbase + ((n_) << 14);                  \
    bfr0 = *(const us8*)(wn_);                                         \
    bfr1 = *(const us8*)(wn_ + 512);                                   \
    bfr2 = *(const us8*)(wn_ + 4096);                                  \
    bfr3 = *(const us8*)(wn_ + 4096 + 512);                            \
    bfr4 = *(const us8*)(wn_ + 8192);                                  \
    bfr5 = *(const us8*)(wn_ + 8192 + 512);                            \
    bfr6 = *(const us8*)(wn_ + 12288);                                 \
    bfr7 = *(const us8*)(wn_ + 12288 + 512);                           \
    __builtin_amdgcn_sched_barrier(0);                                 \
  } while (0)

#define MSTEP(ks_, B0, B1) do {                                        \
    bf16x8 a0_ = __builtin_bit_cast(bf16x8, *(const us8*)(&As[d][mtile + col][(ks_) * 32 + quad * 8]));      \
    bf16x8 a1_ = __builtin_bit_cast(bf16x8, *(const us8*)(&As[d][mtile + 16 + col][(ks_) * 32 + quad * 8])); \
    acc00 = __builtin_amdgcn_mfma_f32_16x16x32_bf16(a0_, __builtin_bit_cast(bf16x8, B0), acc00, 0, 0, 0);    \
    acc01 = __builtin_amdgcn_mfma_f32_16x16x32_bf16(a0_, __builtin_bit_cast(bf16x8, B1), acc01, 0, 0, 0);    \
    acc10 = __builtin_amdgcn_mfma_f32_16x16x32_bf16(a1_, __builtin_bit_cast(bf16x8, B0), acc10, 0, 0, 0);    \
    acc11 = __builtin_amdgcn_mfma_f32_16x16x32_bf16(a1_, __builtin_bit_cast(bf16x8, B1), acc11, 0, 0, 0);    \
  } while (0)

__launch_bounds__(NT, 4)   // 128 VGPR cap: 2 blocks/CU
__global__ void deform_kernel(const unsigned short* __restrict__ xb,
                              const float* __restrict__ off,
                              const unsigned short* __restrict__ Wt,
                              const float* __restrict__ bias,
                              float* __restrict__ out) {
    __shared__ unsigned short As[2][TM][LDK];  // double-buffered: 34816 B
    __shared__ int   cB[TM][KN][2];            // packed lt/rb offsets: 4608 B
    __shared__ float cF[TM][KN][2];            // (fy, fx): 4608 B
    // total 44032 B -> 2 blocks/CU (VGPR-capped)

    const int tid = threadIdx.x;
    const int bb   = blockIdx.x & 7;           // XCD swizzle: image b -> XCD b
    const int hh   = blockIdx.x >> 3;
    const int pix0 = (bb << 12) + (hh << 6);

    // ---- phase 0: packed corner offsets + fractions per (p, n) ----
    for (int t = tid; t < TM * KN; t += NT) {
        int p = t & (TM - 1);
        int n = t >> 6;
        float2 o = *(const float2*)(off + (size_t)(pix0 + p) * (2 * KN) + 2 * n);
        float y = (float)(hh - 1) + c_init_i[n] + o.x;
        float x = (float)(p - 1) + c_init_j[n] + o.y;
        y = fminf(fmaxf(y, 0.f), 63.f);
        x = fminf(fmaxf(x, 0.f), 63.f);
        float y0f = floorf(y), x0f = floorf(x);
        int y0 = (int)y0f, x0 = (int)x0f;
        int y1 = (int)ceilf(y), x1 = (int)ceilf(x);
        cB[p][n][0] = (y0 << 13) | (x0 << 7);   // lt element offset
        cB[p][n][1] = (y1 << 13) | (x1 << 7);   // rb element offset
        cF[p][n][0] = y - y0f;
        cF[p][n][1] = x - x0f;
    }

    const int wave = tid >> 6;
    const int lane = tid & 63;
    const int quad = lane >> 4;
    const int col  = lane & 15;
    const int mtile = (wave & 1) * 32;
    const int ntile = (wave >> 1) * 32;
    const int gi    = wave >> 1;

    f32x4 acc00 = {0.f,0.f,0.f,0.f}, acc01 = {0.f,0.f,0.f,0.f};
    f32x4 acc10 = {0.f,0.f,0.f,0.f}, acc11 = {0.f,0.f,0.f,0.f};

    const unsigned short* bb16  = xb + ((size_t)bb << 19);
    const unsigned short* wbase = Wt + (gi << 10) + (lane << 3);

    us8 ltA, rtA, lbA, rbA;
    us8 ltB, rtB, lbB, rbB;
    us8 bfr0, bfr1, bfr2, bfr3, bfr4, bfr5, bfr6, bfr7;

    __syncthreads();   // coords ready

    ISSUE(0, tid, A);  // prologue: tap 0, item 0
    int d = 0;

    for (int n = 0; n < KN; ++n, d ^= 1) {
        ISSUE(n, tid + NT, B);   // item 1 gathers first (critical path)
        LOADB(n);                // B frags ride until MSTEP (post-barrier)
        CONSUME(n, tid, A);
        ISSUE(n + 1 < KN ? n + 1 : n, tid, A);  // next tap item 0: flies over
                                                 // barrier + MFMA phase
        CONSUME(n, tid + NT, B);

        // ONE barrier per tap: lgkmcnt(0) drains our ds_writes to As[d] AND
        // proves our MSTEP(n-1) ds_reads of As[d^1] completed; global loads
        // (gathers + bfr) stay in flight across the barrier.
        asm volatile("s_waitcnt lgkmcnt(0)" ::: "memory");
        __builtin_amdgcn_s_barrier();
        // Hazard proof: wave W writes As[d^1] next tap; As[d] is rewritten only
        // at tap n+2, which is after barrier(n+1); every wave's tap-n reads of
        // As[d] completed before it reached barrier(n+1) (lgkmcnt(0)). Safe.

        MSTEP(0, bfr0, bfr1);
        MSTEP(1, bfr2, bfr3);
        MSTEP(2, bfr4, bfr5);
        MSTEP(3, bfr6, bfr7);
    }

    // ---- epilogue: C/D layout col=lane&15, row=quad*4+reg (HW-verified) ----
#pragma unroll
    for (int b = 0; b < 2; ++b) {
        int f = ntile + b * 16 + col;
        float bv = bias[f];
        const f32x4 ac0 = b ? acc01 : acc00;
        const f32x4 ac1 = b ? acc11 : acc10;
#pragma unroll
        for (int r = 0; r < 4; ++r) {
            int pr0 = pix0 + mtile + quad * 4 + r;
            out[(size_t)pr0 * FF + f] = ac0[r] + bv;
            int pr1 = pr0 + 16;
            out[(size_t)pr1 * FF + f] = ac1[r] + bv;
        }
    }
}

extern "C" void kernel_launch(void* const* d_in, const int* in_sizes, int n_in,
                              void* d_out, int out_size, void* d_ws, size_t ws_size,
                              hipStream_t stream) {
    const float* x    = (const float*)d_in[0];
    const float* off  = (const float*)d_in[1];
    const float* Wk   = (const float*)d_in[2];
    const float* bias = (const float*)d_in[3];
    float* out = (float*)d_out;
    unsigned short* Wt = (unsigned short*)d_ws;            // 294912 B
    unsigned short* xb = (unsigned short*)d_ws + 147456;   // 8 MB bf16 x

    prep_kernel<<<144 + 2048, 256, 0, stream>>>(Wk, Wt, x, xb);
    deform_kernel<<<(8 * HH * WW) / TM, NT, 0, stream>>>(xb, off, Wt, bias, out);
}